// Round 2
// baseline (2906.389 us; speedup 1.0000x reference)
//
#include <hip/hip_runtime.h>
#include <hip/hip_fp16.h>

// ---------------------------------------------------------------------------
// TimmPnPNystromAttention  (B=32, N=1025, C=768, H=12, Dh=64, landmarks=64)
// Round 1: fp32 baseline, workspace cut 435 MB -> 133 MB.
//   Q  (fp32)  -> d_out (QSZ == out_size exactly; dead before proj GEMM)
//   K,V (fp16) -> ws    (50.4 MB each)
//   CTX (fp32) -> aliases K|V block (dead after t1_kernel)
//   QM,KM,MAXC,EXPB,T1,T2,RC,GMX fp32 -> ws (~32 MB)
// ---------------------------------------------------------------------------

constexpr int kN  = 1025;
constexpr int kNT = 32 * kN;      // 32800 tokens
constexpr int kBH = 32 * 12;      // 384

constexpr size_t QSZ  = (size_t)kBH * kN * 64;   // 25190400 == out_size
constexpr size_t QMSZ = (size_t)kBH * 65 * 64;   // 1597440
constexpr size_t SBSZ = (size_t)kBH * 65 * 65;   // 1622400

__device__ __forceinline__ float4 loadh4(const __half* p) {
    const __half2* q = (const __half2*)p;
    float2 a = __half22float2(q[0]);
    float2 b = __half22float2(q[1]);
    return make_float4(a.x, a.y, b.x, b.y);
}

// ---------------- K1: qkv gemm: X(32800x768) @ W(768x2304) + b -------------
// grid(18, 257) block 256.  128x128 tile, 8x8 micro.
__global__ __launch_bounds__(256, 2) void gemm_qkv(
    const float* __restrict__ X, const float* __restrict__ W,
    const float* __restrict__ bias,
    float* __restrict__ Qo, __half* __restrict__ Ko, __half* __restrict__ Vo)
{
    __shared__ float AsT[8][132];   // [k][row]
    __shared__ float Bs[8][132];    // [k][col]
    const int t  = threadIdx.x;
    const int tx = t & 15, ty = t >> 4;
    const int cb = blockIdx.x * 128;
    const int rb = blockIdx.y * 128;

    float acc[8][8];
#pragma unroll
    for (int i = 0; i < 8; ++i)
#pragma unroll
        for (int j = 0; j < 8; ++j) acc[i][j] = 0.f;

    const int ar  = t >> 1;
    const int akq = (t & 1) * 4;
    const int bk  = t >> 5;
    const int bc  = (t & 31) * 4;

    for (int k0 = 0; k0 < 768; k0 += 8) {
        __syncthreads();
        {
            int r = rb + ar;
            float4 v = make_float4(0.f, 0.f, 0.f, 0.f);
            if (r < kNT) v = *(const float4*)(X + (size_t)r * 768 + k0 + akq);
            AsT[akq + 0][ar] = v.x; AsT[akq + 1][ar] = v.y;
            AsT[akq + 2][ar] = v.z; AsT[akq + 3][ar] = v.w;
            float4 w = *(const float4*)(W + (size_t)(k0 + bk) * 2304 + cb + bc);
            *(float4*)&Bs[bk][bc] = w;
        }
        __syncthreads();
#pragma unroll
        for (int kk = 0; kk < 8; ++kk) {
            float a[8], b[8];
            *(float4*)&a[0] = *(const float4*)&AsT[kk][ty * 8];
            *(float4*)&a[4] = *(const float4*)&AsT[kk][ty * 8 + 4];
            *(float4*)&b[0] = *(const float4*)&Bs[kk][tx * 8];
            *(float4*)&b[4] = *(const float4*)&Bs[kk][tx * 8 + 4];
#pragma unroll
            for (int i = 0; i < 8; ++i)
#pragma unroll
                for (int j = 0; j < 8; ++j)
                    acc[i][j] = fmaf(a[i], b[j], acc[i][j]);
        }
    }
    // epilogue: scatter into (B,H,N,64) q (fp32, scaled 1/8) / k,v (fp16)
    const int c0 = cb + tx * 8;
    const int which = c0 / 768;
    const int cm = c0 % 768;
    const int hh = cm >> 6, d0 = cm & 63;
    float bv[8];
#pragma unroll
    for (int j = 0; j < 8; ++j) bv[j] = bias[c0 + j];
#pragma unroll
    for (int i = 0; i < 8; ++i) {
        int r = rb + ty * 8 + i;
        if (r >= kNT) continue;
        int bidx = r / 1025, n = r % 1025;
        size_t off = ((size_t)(bidx * 12 + hh) * 1025 + n) * 64 + d0;
        if (which == 0) {
            float o[8];
#pragma unroll
            for (int j = 0; j < 8; ++j) o[j] = (acc[i][j] + bv[j]) * 0.125f;
            *(float4*)(Qo + off)     = *(float4*)&o[0];
            *(float4*)(Qo + off + 4) = *(float4*)&o[4];
        } else {
            __half* dst = ((which == 1) ? Ko : Vo) + off;
            __half h8[8];
#pragma unroll
            for (int j = 0; j < 8; ++j) h8[j] = __float2half_rn(acc[i][j] + bv[j]);
            *(float4*)dst = *(float4*)h8;   // 8 halves = 16 B
        }
    }
}

// ---------------- K2: landmark pooling -------------------------------------
// grid(65, 384, 2) block 64.  z=0: Q(fp32)->QM ; z=1: K(fp16)->KM
__global__ __launch_bounds__(64) void pool_kernel(
    const float* __restrict__ Qf, const __half* __restrict__ Kh,
    float* __restrict__ QM, float* __restrict__ KM)
{
    const int d  = threadIdx.x;
    const int m  = blockIdx.x;
    const int bh = blockIdx.y;
    float v;
    if (blockIdx.z == 0) {
        const float* sb = Qf + (size_t)bh * kN * 64;
        if (m == 0) {
            v = sb[d];
        } else {
            int l = m - 1, a = l >> 3, e = l & 7;
            const float* base = sb + (size_t)(1 + a * 128 + e * 4) * 64 + d;
            float s = 0.f;
#pragma unroll
            for (int b4 = 0; b4 < 4; ++b4)
#pragma unroll
                for (int f = 0; f < 4; ++f)
                    s += base[(b4 * 32 + f) * 64];
            v = s * 0.0625f;
        }
        QM[(size_t)bh * 65 * 64 + m * 64 + d] = v;
    } else {
        const __half* sb = Kh + (size_t)bh * kN * 64;
        if (m == 0) {
            v = __half2float(sb[d]);
        } else {
            int l = m - 1, a = l >> 3, e = l & 7;
            const __half* base = sb + (size_t)(1 + a * 128 + e * 4) * 64 + d;
            float s = 0.f;
#pragma unroll
            for (int b4 = 0; b4 < 4; ++b4)
#pragma unroll
                for (int f = 0; f < 4; ++f)
                    s += __half2float(base[(b4 * 32 + f) * 64]);
            v = s * 0.0625f;
        }
        KM[(size_t)bh * 65 * 64 + m * 64 + d] = v;
    }
}

// ---------------- K3: maxC[bh][m] = max_n qm[m].k[n] -----------------------
__global__ __launch_bounds__(256) void maxc_kernel(
    const float* __restrict__ QM, const __half* __restrict__ Kg,
    float* __restrict__ MAXC)
{
    __shared__ float QmT[64][68];   // [k][m]
    __shared__ float KtT[64][68];   // [k][nn]
    __shared__ float red[65][17];
    const int t = threadIdx.x, bh = blockIdx.x;
    const float* qm = QM + (size_t)bh * 4160;
    const __half* Kb = Kg + (size_t)bh * 65600;

    for (int s = 0; s < 5; ++s) {
        int idx = t + s * 256;
        if (idx < 1040) {
            int r = idx >> 4, c = idx & 15;
            float4 v = *(const float4*)(qm + r * 64 + c * 4);
            QmT[c * 4 + 0][r] = v.x; QmT[c * 4 + 1][r] = v.y;
            QmT[c * 4 + 2][r] = v.z; QmT[c * 4 + 3][r] = v.w;
        }
    }
    const int tm = t >> 4, tn = t & 15;
    float mx[5];
#pragma unroll
    for (int i = 0; i < 5; ++i) mx[i] = -3.4e38f;

    for (int nt = 0; nt < 17; ++nt) {
        const int n0 = nt * 64;
        __syncthreads();
        for (int s = 0; s < 4; ++s) {
            int idx = t + s * 256;
            int r = idx >> 4, c = idx & 15;
            int n = n0 + r;
            float4 v = make_float4(0.f, 0.f, 0.f, 0.f);
            if (n < kN) v = loadh4(Kb + (size_t)n * 64 + c * 4);
            KtT[c * 4 + 0][r] = v.x; KtT[c * 4 + 1][r] = v.y;
            KtT[c * 4 + 2][r] = v.z; KtT[c * 4 + 3][r] = v.w;
        }
        __syncthreads();
        float acc[5][4];
#pragma unroll
        for (int i = 0; i < 5; ++i)
#pragma unroll
            for (int j = 0; j < 4; ++j) acc[i][j] = 0.f;
        for (int k = 0; k < 64; ++k) {
            float a[5], b[4];
            float4 av = *(const float4*)&QmT[k][tm * 4];
            a[0] = av.x; a[1] = av.y; a[2] = av.z; a[3] = av.w;
            a[4] = (tm == 0) ? QmT[k][64] : 0.f;
            float4 bv = *(const float4*)&KtT[k][tn * 4];
            b[0] = bv.x; b[1] = bv.y; b[2] = bv.z; b[3] = bv.w;
#pragma unroll
            for (int i = 0; i < 5; ++i)
#pragma unroll
                for (int j = 0; j < 4; ++j)
                    acc[i][j] = fmaf(a[i], b[j], acc[i][j]);
        }
#pragma unroll
        for (int j = 0; j < 4; ++j) {
            if (n0 + tn * 4 + j < kN) {
#pragma unroll
                for (int i = 0; i < 5; ++i) mx[i] = fmaxf(mx[i], acc[i][j]);
            }
        }
    }
    __syncthreads();
#pragma unroll
    for (int i = 0; i < 4; ++i) red[tm * 4 + i][tn] = mx[i];
    if (tm == 0) red[64][tn] = mx[4];
    __syncthreads();
    if (t < 65) {
        float v = red[t][0];
        for (int c = 1; c < 16; ++c) v = fmaxf(v, red[t][c]);
        MAXC[(size_t)bh * 65 + t] = v;
    }
}

// ---------------- K4: expB = exp(max(qm@km^T - maxC, -88)); row/col maxima --
__global__ __launch_bounds__(256) void expb_kernel(
    const float* __restrict__ QM, const float* __restrict__ KM,
    const float* __restrict__ MAXC, float* __restrict__ EXPB,
    float* __restrict__ RC)
{
    __shared__ float Qs[65][68];
    __shared__ float Ks[65][68];
    __shared__ float SB[65][68];
    __shared__ float mc[65];
    __shared__ float rs[65], cs[65];
    const int t = threadIdx.x, bh = blockIdx.x;
    const float* qm = QM + (size_t)bh * 4160;
    const float* km = KM + (size_t)bh * 4160;
    for (int s = 0; s < 5; ++s) {
        int idx = t + s * 256;
        if (idx < 1040) {
            int r = idx >> 4, c = (idx & 15) * 4;
            *(float4*)&Qs[r][c] = *(const float4*)(qm + r * 64 + c);
            *(float4*)&Ks[r][c] = *(const float4*)(km + r * 64 + c);
        }
    }
    if (t < 65) mc[t] = MAXC[(size_t)bh * 65 + t];
    __syncthreads();
    for (int s = 0; s < 17; ++s) {
        int o = t + s * 256;
        if (o < 4225) {
            int i = o / 65, j = o % 65;
            float av = 0.f;
            for (int k = 0; k < 64; k += 4) {
                float4 a = *(const float4*)&Qs[i][k];
                float4 b = *(const float4*)&Ks[j][k];
                av = fmaf(a.x, b.x, av); av = fmaf(a.y, b.y, av);
                av = fmaf(a.z, b.z, av); av = fmaf(a.w, b.w, av);
            }
            float e = __expf(fmaxf(av - mc[i], -88.f));
            SB[i][j] = e;
            EXPB[(size_t)bh * 4225 + o] = e;
        }
    }
    __syncthreads();
    if (t < 65) {
        float r = 0.f, c = 0.f;
        for (int j = 0; j < 65; ++j) r += SB[t][j];
        for (int i = 0; i < 65; ++i) c += SB[i][t];
        rs[t] = r; cs[t] = c;
    }
    __syncthreads();
    if (t == 0) {
        float rm = 0.f, cm2 = 0.f;
        for (int i = 0; i < 65; ++i) { rm = fmaxf(rm, rs[i]); cm2 = fmaxf(cm2, cs[i]); }
        RC[bh * 2] = rm; RC[bh * 2 + 1] = cm2;
    }
}

// ---------------- K5: alpha = 1/(global_max_rowsum * global_max_colsum + eps)
__global__ __launch_bounds__(256) void alpha_kernel(
    const float* __restrict__ RC, float* __restrict__ GMX)
{
    __shared__ float sr[256], sc[256];
    const int t = threadIdx.x;
    float rm = 0.f, cm = 0.f;   // sums are >= 0
    for (int i = t; i < kBH; i += 256) {
        rm = fmaxf(rm, RC[2 * i]);
        cm = fmaxf(cm, RC[2 * i + 1]);
    }
    sr[t] = rm; sc[t] = cm;
    __syncthreads();
    for (int s = 128; s > 0; s >>= 1) {
        if (t < s) { sr[t] = fmaxf(sr[t], sr[t + s]); sc[t] = fmaxf(sc[t], sc[t + s]); }
        __syncthreads();
    }
    if (t == 0) GMX[0] = 1.f / (sr[0] * sc[0] + 1e-15f);
}

// ---------------- K7: T1 = expC @ v_aug  (recompute S_C; no expC storage) ---
__global__ __launch_bounds__(256) void t1_kernel(
    const float* __restrict__ QM, const __half* __restrict__ Kg,
    const __half* __restrict__ Vg, const float* __restrict__ MAXC,
    float* __restrict__ T1)
{
    __shared__ float QmT[64][68];   // [k][m]
    __shared__ float Wt[64][68];    // K-tile transposed (phase1) / V-tile (phase2)
    __shared__ float ET[64][68];    // [nn][m] expC tile
    __shared__ float mc[65];
    const int t = threadIdx.x, bh = blockIdx.x;
    const float* qm = QM + (size_t)bh * 4160;
    const __half* Kb = Kg + (size_t)bh * 65600;
    const __half* Vb = Vg + (size_t)bh * 65600;

    for (int s = 0; s < 5; ++s) {
        int idx = t + s * 256;
        if (idx < 1040) {
            int r = idx >> 4, c = idx & 15;
            float4 v = *(const float4*)(qm + r * 64 + c * 4);
            QmT[c * 4 + 0][r] = v.x; QmT[c * 4 + 1][r] = v.y;
            QmT[c * 4 + 2][r] = v.z; QmT[c * 4 + 3][r] = v.w;
        }
    }
    if (t < 65) mc[t] = MAXC[(size_t)bh * 65 + t];
    const int tm = t >> 4, tn = t & 15;
    float acc2[5][5];
#pragma unroll
    for (int i = 0; i < 5; ++i)
#pragma unroll
        for (int j = 0; j < 5; ++j) acc2[i][j] = 0.f;

    for (int nt = 0; nt < 17; ++nt) {
        const int n0 = nt * 64;
        __syncthreads();
        for (int s = 0; s < 4; ++s) {
            int idx = t + s * 256;
            int r = idx >> 4, c = idx & 15;
            int n = n0 + r;
            float4 v = make_float4(0.f, 0.f, 0.f, 0.f);
            if (n < kN) v = loadh4(Kb + (size_t)n * 64 + c * 4);
            Wt[c * 4 + 0][r] = v.x; Wt[c * 4 + 1][r] = v.y;
            Wt[c * 4 + 2][r] = v.z; Wt[c * 4 + 3][r] = v.w;
        }
        __syncthreads();
        {   // phase1: dots -> exp -> ET
            float acc[5][4];
#pragma unroll
            for (int i = 0; i < 5; ++i)
#pragma unroll
                for (int j = 0; j < 4; ++j) acc[i][j] = 0.f;
            for (int k = 0; k < 64; ++k) {
                float a[5], b[4];
                float4 av = *(const float4*)&QmT[k][tm * 4];
                a[0] = av.x; a[1] = av.y; a[2] = av.z; a[3] = av.w;
                a[4] = (tm == 0) ? QmT[k][64] : 0.f;
                float4 bv = *(const float4*)&Wt[k][tn * 4];
                b[0] = bv.x; b[1] = bv.y; b[2] = bv.z; b[3] = bv.w;
#pragma unroll
                for (int i = 0; i < 5; ++i)
#pragma unroll
                    for (int j = 0; j < 4; ++j)
                        acc[i][j] = fmaf(a[i], b[j], acc[i][j]);
            }
#pragma unroll
            for (int j = 0; j < 4; ++j) {
                int nn = tn * 4 + j;
                bool valid = (n0 + nn) < kN;
#pragma unroll
                for (int i = 0; i < 4; ++i)
                    ET[nn][tm * 4 + i] = valid ? __expf(acc[i][j] - mc[tm * 4 + i]) : 0.f;
                if (tm == 0)
                    ET[nn][64] = valid ? __expf(acc[4][j] - mc[64]) : 0.f;
            }
        }
        __syncthreads();
        for (int s = 0; s < 4; ++s) {   // stage V tile (natural layout) + ones
            int idx = t + s * 256;
            int r = idx >> 4, c = idx & 15;
            int n = n0 + r;
            float4 v = make_float4(0.f, 0.f, 0.f, 0.f);
            if (n < kN) v = loadh4(Vb + (size_t)n * 64 + c * 4);
            *(float4*)&Wt[r][c * 4] = v;
        }
        if (t < 64) Wt[t][64] = 1.f;
        __syncthreads();
        for (int nn = 0; nn < 64; ++nn) {   // phase2: T1 += E^T-style product
            float a[5], b[5];
            float4 av = *(const float4*)&ET[nn][tm * 4];
            a[0] = av.x; a[1] = av.y; a[2] = av.z; a[3] = av.w;
            a[4] = (tm == 0) ? ET[nn][64] : 0.f;
            float4 bv = *(const float4*)&Wt[nn][tn * 4];
            b[0] = bv.x; b[1] = bv.y; b[2] = bv.z; b[3] = bv.w;
            b[4] = (tn == 0) ? Wt[nn][64] : 0.f;
#pragma unroll
            for (int i = 0; i < 5; ++i)
#pragma unroll
                for (int j = 0; j < 5; ++j)
                    acc2[i][j] = fmaf(a[i], b[j], acc2[i][j]);
        }
    }
    float* T1b = T1 + (size_t)bh * 4225;
#pragma unroll
    for (int i = 0; i < 5; ++i) {
        if (i == 4 && tm != 0) continue;
        int m = (i < 4) ? tm * 4 + i : 64;
#pragma unroll
        for (int j = 0; j < 5; ++j) {
            if (j == 4 && tn != 0) continue;
            int jc = (j < 4) ? tn * 4 + j : 64;
            T1b[m * 65 + jc] = acc2[i][j];
        }
    }
}

// ---------------- K6: Newton-Schulz pinv (6 iters) + T2 = Z @ T1 ------------
__device__ __forceinline__ void mm65(const float (*Op1)[68], const float (*Op2)[68],
                                     float (*Dst)[68], const float (*Pre)[68],
                                     float c0, float c1, int tm, int tj)
{
    float acc[5][5];
#pragma unroll
    for (int i = 0; i < 5; ++i)
#pragma unroll
        for (int j = 0; j < 5; ++j) acc[i][j] = 0.f;
    for (int k = 0; k < 65; ++k) {
        float a[5], b[5];
        a[0] = Op1[tm * 4 + 0][k]; a[1] = Op1[tm * 4 + 1][k];
        a[2] = Op1[tm * 4 + 2][k]; a[3] = Op1[tm * 4 + 3][k];
        a[4] = (tm == 0) ? Op1[64][k] : 0.f;
        float4 bv = *(const float4*)&Op2[k][tj * 4];
        b[0] = bv.x; b[1] = bv.y; b[2] = bv.z; b[3] = bv.w;
        b[4] = (tj == 0) ? Op2[k][64] : 0.f;
#pragma unroll
        for (int i = 0; i < 5; ++i)
#pragma unroll
            for (int j = 0; j < 5; ++j)
                acc[i][j] = fmaf(a[i], b[j], acc[i][j]);
    }
    float val[5][5];
#pragma unroll
    for (int i = 0; i < 5; ++i) {
        int mi = (i < 4) ? tm * 4 + i : 64;
#pragma unroll
        for (int j = 0; j < 5; ++j) {
            int jc = (j < 4) ? tj * 4 + j : 64;
            val[i][j] = c1 * (c0 * Pre[mi][jc] - acc[i][j]);
        }
    }
    __syncthreads();
#pragma unroll
    for (int i = 0; i < 5; ++i) {
        if (i == 4 && tm != 0) continue;
        int mi = (i < 4) ? tm * 4 + i : 64;
#pragma unroll
        for (int j = 0; j < 5; ++j) {
            if (j == 4 && tj != 0) continue;
            int jc = (j < 4) ? tj * 4 + j : 64;
            Dst[mi][jc] = val[i][j];
        }
    }
    __syncthreads();
}

__global__ __launch_bounds__(256) void pinv_kernel(
    const float* __restrict__ EXPB, const float* __restrict__ T1,
    const float* __restrict__ GMX, float* __restrict__ T2)
{
    __shared__ float Wb[65][68];
    __shared__ float Zb[65][68];
    __shared__ float Ab[65][68];
    const int t = threadIdx.x, bh = blockIdx.x;
    const int tm = t >> 4, tj = t & 15;
    const float alpha = GMX[0];
    const float* X = EXPB + (size_t)bh * 4225;
    for (int s = 0; s < 17; ++s) {
        int o = t + s * 256;
        if (o < 4225) Wb[o / 65][o % 65] = X[o];
    }
    __syncthreads();
    for (int s = 0; s < 17; ++s) {   // Z = alpha * X^T
        int o = t + s * 256;
        if (o < 4225) { int i = o / 65, j = o % 65; Zb[i][j] = alpha * Wb[j][i]; }
    }
    __syncthreads();
    for (int it = 0; it < 6; ++it) {
        if (it > 0) {   // W was clobbered by U last iter; restage X
            for (int s = 0; s < 17; ++s) {
                int o = t + s * 256;
                if (o < 4225) Wb[o / 65][o % 65] = X[o];
            }
            __syncthreads();
        }
        mm65(Wb, Zb, Ab, Wb, 0.f,  -1.f,  tm, tj);  // A = X@Z
        mm65(Ab, Ab, Wb, Ab, 7.f,   1.f,  tm, tj);  // U = 7A - A@A    -> W
        mm65(Ab, Wb, Ab, Ab, 15.f,  1.f,  tm, tj);  // V = 15A - A@U   -> A
        mm65(Zb, Ab, Zb, Zb, 13.f,  0.25f, tm, tj); // Z = .25(13Z - Z@V)
    }
    for (int s = 0; s < 17; ++s) {   // stage T1 -> W
        int o = t + s * 256;
        if (o < 4225) Wb[o / 65][o % 65] = T1[(size_t)bh * 4225 + o];
    }
    __syncthreads();
    {   // T2 = Z @ T1 (to global)
        float acc[5][5];
#pragma unroll
        for (int i = 0; i < 5; ++i)
#pragma unroll
            for (int j = 0; j < 5; ++j) acc[i][j] = 0.f;
        for (int k = 0; k < 65; ++k) {
            float a[5], b[5];
            a[0] = Zb[tm * 4 + 0][k]; a[1] = Zb[tm * 4 + 1][k];
            a[2] = Zb[tm * 4 + 2][k]; a[3] = Zb[tm * 4 + 3][k];
            a[4] = (tm == 0) ? Zb[64][k] : 0.f;
            float4 bv = *(const float4*)&Wb[k][tj * 4];
            b[0] = bv.x; b[1] = bv.y; b[2] = bv.z; b[3] = bv.w;
            b[4] = (tj == 0) ? Wb[k][64] : 0.f;
#pragma unroll
            for (int i = 0; i < 5; ++i)
#pragma unroll
                for (int j = 0; j < 5; ++j)
                    acc[i][j] = fmaf(a[i], b[j], acc[i][j]);
        }
        float* dst = T2 + (size_t)bh * 4225;
#pragma unroll
        for (int i = 0; i < 5; ++i) {
            if (i == 4 && tm != 0) continue;
            int mi = (i < 4) ? tm * 4 + i : 64;
#pragma unroll
            for (int j = 0; j < 5; ++j) {
                if (j == 4 && tj != 0) continue;
                int jc = (j < 4) ? tj * 4 + j : 64;
                dst[mi * 65 + jc] = acc[i][j];
            }
        }
    }
}

// ---------------- K8: prod = expA @ T2 ; ctx = prod[:,:64]/max(prod[:,64],1e-8)
__global__ __launch_bounds__(256) void prod_kernel(
    const float* __restrict__ Qg, const float* __restrict__ KM,
    const float* __restrict__ T2, float* __restrict__ CTX)
{
    __shared__ float Sh1[65][68];   // KmT [k][m] (phase1) then T2 [m][j] (phase2)
    __shared__ float QtT[64][68];   // [k][nn]
    __shared__ float EA[64][69];    // raw S -> expA -> ctx-tile
    __shared__ float den[64];
    __shared__ float pm[64][4];
    const int t  = threadIdx.x;
    const int nt = blockIdx.x, bh = blockIdx.y;
    const int bq = bh / 12, h = bh % 12;
    const int n0 = nt * 64;
    const float* km = KM + (size_t)bh * 4160;
    const float* Qb = Qg + (size_t)bh * 65600;

    for (int s = 0; s < 5; ++s) {
        int idx = t + s * 256;
        if (idx < 1040) {
            int r = idx >> 4, c = idx & 15;
            float4 v = *(const float4*)(km + r * 64 + c * 4);
            Sh1[c * 4 + 0][r] = v.x; Sh1[c * 4 + 1][r] = v.y;
            Sh1[c * 4 + 2][r] = v.z; Sh1[c * 4 + 3][r] = v.w;
        }
    }
    for (int s = 0; s < 4; ++s) {
        int idx = t + s * 256;
        int r = idx >> 4, c = idx & 15;
        int n = n0 + r;
        float4 v = make_float4(0.f, 0.f, 0.f, 0.f);
        if (n < kN) v = *(const float4*)(Qb + (size_t)n * 64 + c * 4);
        QtT[c * 4 + 0][r] = v.x; QtT[c * 4 + 1][r] = v.y;
        QtT[c * 4 + 2][r] = v.z; QtT[c * 4 + 3][r] = v.w;
    }
    __syncthreads();
    {   // phase1: raw S_A tile
        const int tm = t >> 4, tn = t & 15;
        float acc[5][4];
#pragma unroll
        for (int i = 0; i < 5; ++i)
#pragma unroll
            for (int j = 0; j < 4; ++j) acc[i][j] = 0.f;
        for (int k = 0; k < 64; ++k) {
            float a[5], b[4];
            float4 av = *(const float4*)&Sh1[k][tm * 4];
            a[0] = av.x; a[1] = av.y; a[2] = av.z; a[3] = av.w;
            a[4] = (tm == 0) ? Sh1[k][64] : 0.f;
            float4 bv = *(const float4*)&QtT[k][tn * 4];
            b[0] = bv.x; b[1] = bv.y; b[2] = bv.z; b[3] = bv.w;
#pragma unroll
            for (int i = 0; i < 5; ++i)
#pragma unroll
                for (int j = 0; j < 4; ++j)
                    acc[i][j] = fmaf(a[i], b[j], acc[i][j]);
        }
#pragma unroll
        for (int j = 0; j < 4; ++j) {
            int nn = tn * 4 + j;
#pragma unroll
            for (int i = 0; i < 4; ++i) EA[nn][tm * 4 + i] = acc[i][j];
            if (tm == 0) EA[nn][64] = acc[4][j];
        }
    }
    __syncthreads();
    {   // row max + exp (per q-row over 65 landmarks)
        const int rr = t & 63, mg = t >> 6;
        float mx = -3.4e38f;
        for (int s = 0; s < 17; ++s) { int m = mg + 4 * s; if (m < 65) mx = fmaxf(mx, EA[rr][m]); }
        pm[rr][mg] = mx;
        __syncthreads();
        float mt2 = fmaxf(fmaxf(pm[rr][0], pm[rr][1]), fmaxf(pm[rr][2], pm[rr][3]));
        for (int s = 0; s < 17; ++s) { int m = mg + 4 * s; if (m < 65) EA[rr][m] = __expf(EA[rr][m] - mt2); }
    }
    for (int s = 0; s < 17; ++s) {   // stage T2 (overwrites KmT; phase1 done)
        int o = t + s * 256;
        if (o < 4225) Sh1[o / 65][o % 65] = T2[(size_t)bh * 4225 + o];
    }
    __syncthreads();
    {   // phase2: prod = EA @ T2, then divide, stash ctx tile back into EA
        const int tr = t & 15, tjg = t >> 4;
        float acc2[4][5];
#pragma unroll
        for (int i = 0; i < 4; ++i)
#pragma unroll
            for (int j = 0; j < 5; ++j) acc2[i][j] = 0.f;
        for (int m = 0; m < 65; ++m) {
            float a[4], b[5];
            a[0] = EA[tr * 4 + 0][m]; a[1] = EA[tr * 4 + 1][m];
            a[2] = EA[tr * 4 + 2][m]; a[3] = EA[tr * 4 + 3][m];
            float4 bv = *(const float4*)&Sh1[m][tjg * 4];
            b[0] = bv.x; b[1] = bv.y; b[2] = bv.z; b[3] = bv.w;
            b[4] = (tjg == 0) ? Sh1[m][64] : 0.f;
#pragma unroll
            for (int i = 0; i < 4; ++i)
#pragma unroll
                for (int j = 0; j < 5; ++j)
                    acc2[i][j] = fmaf(a[i], b[j], acc2[i][j]);
        }
        if (tjg == 0) {
#pragma unroll
            for (int ii = 0; ii < 4; ++ii) den[tr * 4 + ii] = acc2[ii][4];
        }
        __syncthreads();   // den ready; also all EA reads complete
#pragma unroll
        for (int ii = 0; ii < 4; ++ii) {
            int nn = tr * 4 + ii;
            float dv = fmaxf(den[nn], 1e-8f);
#pragma unroll
            for (int jj = 0; jj < 4; ++jj)
                EA[nn][tjg * 4 + jj] = acc2[ii][jj] / dv;
        }
    }
    __syncthreads();
    {   // coalesced write: ctx[b, n, h*64 + c]
        const int c = t & 63, rg = t >> 6;
        for (int s = 0; s < 16; ++s) {
            int r = rg + 4 * s;
            int n = n0 + r;
            if (n < kN)
                CTX[((size_t)bq * 1025 + n) * 768 + h * 64 + c] = EA[r][c];
        }
    }
}

// ---------------- K9: out = CTX(32800x768) @ proj_w(768x768) + proj_b -------
__global__ __launch_bounds__(256, 2) void gemm_proj(
    const float* __restrict__ A, const float* __restrict__ W,
    const float* __restrict__ bias, float* __restrict__ Out)
{
    __shared__ float AsT[8][132];
    __shared__ float Bs[8][132];
    const int t  = threadIdx.x;
    const int tx = t & 15, ty = t >> 4;
    const int cb = blockIdx.x * 128;
    const int rb = blockIdx.y * 128;
    float acc[8][8];
#pragma unroll
    for (int i = 0; i < 8; ++i)
#pragma unroll
        for (int j = 0; j < 8; ++j) acc[i][j] = 0.f;
    const int ar  = t >> 1;
    const int akq = (t & 1) * 4;
    const int bk  = t >> 5;
    const int bc  = (t & 31) * 4;
    for (int k0 = 0; k0 < 768; k0 += 8) {
        __syncthreads();
        {
            int r = rb + ar;
            float4 v = make_float4(0.f, 0.f, 0.f, 0.f);
            if (r < kNT) v = *(const float4*)(A + (size_t)r * 768 + k0 + akq);
            AsT[akq + 0][ar] = v.x; AsT[akq + 1][ar] = v.y;
            AsT[akq + 2][ar] = v.z; AsT[akq + 3][ar] = v.w;
            float4 w = *(const float4*)(W + (size_t)(k0 + bk) * 768 + cb + bc);
            *(float4*)&Bs[bk][bc] = w;
        }
        __syncthreads();
#pragma unroll
        for (int kk = 0; kk < 8; ++kk) {
            float a[8], b[8];
            *(float4*)&a[0] = *(const float4*)&AsT[kk][ty * 8];
            *(float4*)&a[4] = *(const float4*)&AsT[kk][ty * 8 + 4];
            *(float4*)&b[0] = *(const float4*)&Bs[kk][tx * 8];
            *(float4*)&b[4] = *(const float4*)&Bs[kk][tx * 8 + 4];
#pragma unroll
            for (int i = 0; i < 8; ++i)
#pragma unroll
                for (int j = 0; j < 8; ++j)
                    acc[i][j] = fmaf(a[i], b[j], acc[i][j]);
        }
    }
    const int c0 = cb + tx * 8;
    float bv[8];
#pragma unroll
    for (int j = 0; j < 8; ++j) bv[j] = bias[c0 + j];
#pragma unroll
    for (int i = 0; i < 8; ++i) {
        int r = rb + ty * 8 + i;
        if (r >= kNT) continue;
        float o[8];
#pragma unroll
        for (int j = 0; j < 8; ++j) o[j] = acc[i][j] + bv[j];
        *(float4*)(Out + (size_t)r * 768 + c0)     = *(float4*)&o[0];
        *(float4*)(Out + (size_t)r * 768 + c0 + 4) = *(float4*)&o[4];
    }
}

// ---------------------------------------------------------------------------
extern "C" void kernel_launch(void* const* d_in, const int* in_sizes, int n_in,
                              void* d_out, int out_size, void* d_ws, size_t ws_size,
                              hipStream_t stream)
{
    const float* x      = (const float*)d_in[0];
    const float* qkv_w  = (const float*)d_in[1];
    const float* qkv_b  = (const float*)d_in[2];
    const float* proj_w = (const float*)d_in[3];
    const float* proj_b = (const float*)d_in[4];
    float* out = (float*)d_out;

    // Q (fp32) lives in d_out: QSZ == out_size; Q is dead before gemm_proj.
    float* Q = (float*)d_out;

    // ws: [ K(fp16) | V(fp16) ] == CTX(fp32) alias, then small fp32 buffers.
    float* base = (float*)d_ws;
    __half* Kh  = (__half*)base;          // QSZ halves
    __half* Vh  = Kh + QSZ;               // QSZ halves
    float* CTX  = base;                   // QSZ floats, aliases Kh|Vh (dead then)
    float* QM   = base + QSZ;
    float* KM   = QM + QMSZ;
    float* MAXC = KM + QMSZ;
    float* EXPB = MAXC + (size_t)kBH * 65;
    float* T1   = EXPB + SBSZ;
    float* T2   = T1 + SBSZ;
    float* RC   = T2 + SBSZ;
    // float* GMX = RC + kBH * 2;  (below)
    float* GMX  = RC + (size_t)kBH * 2;

    gemm_qkv <<<dim3(18, 257), 256, 0, stream>>>(x, qkv_w, qkv_b, Q, Kh, Vh);
    pool_kernel<<<dim3(65, kBH, 2), 64, 0, stream>>>(Q, Kh, QM, KM);
    maxc_kernel<<<dim3(kBH), 256, 0, stream>>>(QM, Kh, MAXC);
    expb_kernel<<<dim3(kBH), 256, 0, stream>>>(QM, KM, MAXC, EXPB, RC);
    alpha_kernel<<<dim3(1), 256, 0, stream>>>(RC, GMX);
    t1_kernel  <<<dim3(kBH), 256, 0, stream>>>(QM, Kh, Vh, MAXC, T1);
    pinv_kernel<<<dim3(kBH), 256, 0, stream>>>(EXPB, T1, GMX, T2);
    prod_kernel<<<dim3(17, kBH), 256, 0, stream>>>(Q, KM, T2, CTX);
    gemm_proj  <<<dim3(6, 257), 256, 0, stream>>>(CTX, proj_w, proj_b, out);
}

// Round 3
// 1235.497 us; speedup vs baseline: 2.3524x; 2.3524x over previous
//
#include <hip/hip_runtime.h>
#include <hip/hip_fp16.h>

// ---------------------------------------------------------------------------
// TimmPnPNystromAttention  (B=32, N=1025, C=768, H=12, Dh=64, landmarks=64)
// Round 3: fp16 MFMA for both big GEMMs (m97-style: 128x128 tile, BK=64,
// global_load_lds w=16, XOR-swizzled LDS, mfma_f32_16x16x32_f16).
//
// d_out (100.8 MB): [ Xh fp16 (50.4) | Qh fp16 (50.4) ]  -> final fp32 out
// ws (137.8 MB): Kh | Vh (fp16, CTXh aliases Kh) | fp32 smalls | WT fp16
// ---------------------------------------------------------------------------

constexpr int kN  = 1025;
constexpr int kNT = 32 * kN;      // 32800 tokens
constexpr int kBH = 32 * 12;      // 384

constexpr size_t QSZ  = (size_t)kBH * kN * 64;   // 25190400 == out_size
constexpr size_t QMSZ = (size_t)kBH * 65 * 64;   // 1597440
constexpr size_t SBSZ = (size_t)kBH * 65 * 65;   // 1622400

typedef _Float16 f16x8 __attribute__((ext_vector_type(8)));
typedef float    f32x4 __attribute__((ext_vector_type(4)));

#define GLDS(gp, lp) __builtin_amdgcn_global_load_lds( \
    (const __attribute__((address_space(1))) void*)(gp), \
    (__attribute__((address_space(3))) void*)(lp), 16, 0, 0)

__device__ __forceinline__ float4 loadh4(const __half* p) {
    const __half2* q = (const __half2*)p;
    float2 a = __half22float2(q[0]);
    float2 b = __half22float2(q[1]);
    return make_float4(a.x, a.y, b.x, b.y);
}

// ---------------- K0a: fp32 -> fp16 elementwise (X) -------------------------
__global__ __launch_bounds__(256) void cvt_f32_f16(
    const float* __restrict__ src, __half* __restrict__ dst, int n4)
{
    int i = blockIdx.x * 256 + threadIdx.x;
    if (i < n4) {
        float4 v = ((const float4*)src)[i];
        __half2 h01 = __floats2half2_rn(v.x, v.y);
        __half2 h23 = __floats2half2_rn(v.z, v.w);
        ((__half2*)dst)[2 * i]     = h01;
        ((__half2*)dst)[2 * i + 1] = h23;
    }
}

// ---------------- K0b: W (rows x cols, fp32) -> WT (cols x rows, fp16) ------
__global__ __launch_bounds__(256) void cvt_transpose(
    const float* __restrict__ W, __half* __restrict__ WT, int rows, int cols)
{
    __shared__ float tile[32][33];
    const int n0 = blockIdx.x * 32, k0 = blockIdx.y * 32;
#pragma unroll
    for (int i = 0; i < 4; ++i)
        tile[threadIdx.y + i * 8][threadIdx.x] =
            W[(size_t)(k0 + threadIdx.y + i * 8) * cols + n0 + threadIdx.x];
    __syncthreads();
#pragma unroll
    for (int i = 0; i < 4; ++i)
        WT[(size_t)(n0 + threadIdx.y + i * 8) * rows + k0 + threadIdx.x] =
            __float2half_rn(tile[threadIdx.x][threadIdx.y + i * 8]);
}

// ---------------- K1/K9: fp16 MFMA GEMM, 128x128 tile, BK=64 ----------------
// A: M x 768 fp16 (k-contig); Bt: N x 768 fp16 (k-contig).
// MODE 0: qkv epilogue -> Qh(*0.125)/Kh/Vh fp16 scatter. MODE 1: fp32 out+bias.
template<int MODE>
__global__ __launch_bounds__(256) void gemm_mfma(
    const __half* __restrict__ A, const __half* __restrict__ Bt,
    const float* __restrict__ bias,
    float* __restrict__ OutF, __half* __restrict__ Qo,
    __half* __restrict__ Ko, __half* __restrict__ Vo)
{
    __shared__ _Float16 As[128 * 64];
    __shared__ _Float16 Bs[128 * 64];
    const int t  = threadIdx.x;
    const int w  = t >> 6, L = t & 63;
    const int q  = L >> 4, ln = L & 15;
    const int wm = w >> 1, wn = w & 1;
    const int cb = blockIdx.x * 128, rb = blockIdx.y * 128;

    f32x4 acc[4][4];
#pragma unroll
    for (int i = 0; i < 4; ++i)
#pragma unroll
        for (int j = 0; j < 4; ++j) acc[i][j] = (f32x4)0.f;

    const int srow = L >> 3;   // 0..7  (row within 8-row staging group)
    const int sc   = L & 7;    // chunk slot within row (8 halves each)

    for (int kt = 0; kt < 12; ++kt) {
        const int k0 = kt * 64;
        __syncthreads();
#pragma unroll
        for (int i = 0; i < 4; ++i) {
            const int r0  = w * 32 + i * 8;
            const int row = r0 + srow;
            const int g   = sc ^ (row & 7);      // XOR swizzle at load time
            if (rb + row < kNT)
                GLDS(A + (size_t)(rb + row) * 768 + k0 + g * 8, &As[r0 * 64]);
            GLDS(Bt + (size_t)(cb + row) * 768 + k0 + g * 8, &Bs[r0 * 64]);
        }
        __syncthreads();
#pragma unroll
        for (int kc = 0; kc < 2; ++kc) {
            f16x8 af[4], bf[4];
#pragma unroll
            for (int im = 0; im < 4; ++im) {
                const int m    = wm * 64 + im * 16 + ln;
                const int slot = (kc * 4 + q) ^ (m & 7);
                af[im] = *(const f16x8*)&As[m * 64 + slot * 8];
            }
#pragma unroll
            for (int in = 0; in < 4; ++in) {
                const int n    = wn * 64 + in * 16 + ln;
                const int slot = (kc * 4 + q) ^ (n & 7);
                bf[in] = *(const f16x8*)&Bs[n * 64 + slot * 8];
            }
#pragma unroll
            for (int im = 0; im < 4; ++im)
#pragma unroll
                for (int in = 0; in < 4; ++in)
                    acc[im][in] = __builtin_amdgcn_mfma_f32_16x16x32_f16(
                        af[im], bf[in], acc[im][in], 0, 0, 0);
        }
    }

    // epilogue: C/D layout col=lane&15, row=quad*4+reg
    float bcol[4];
#pragma unroll
    for (int in = 0; in < 4; ++in) bcol[in] = bias[cb + wn * 64 + in * 16 + ln];

    if (MODE == 0) {
#pragma unroll
        for (int in = 0; in < 4; ++in) {
            const int Ncol  = cb + wn * 64 + in * 16 + ln;
            const int which = Ncol / 768;            // 0=q 1=k 2=v (uniform/16)
            const int cm    = Ncol - which * 768;
            const int h     = cm >> 6, d0 = cm & 63;
            __half* dst = (which == 0) ? Qo : (which == 1) ? Ko : Vo;
            const float scl = (which == 0) ? 0.125f : 1.f;
#pragma unroll
            for (int im = 0; im < 4; ++im) {
                const int Rb2 = rb + wm * 64 + im * 16 + q * 4;
#pragma unroll
                for (int reg = 0; reg < 4; ++reg) {
                    const int R = Rb2 + reg;
                    if (R < kNT) {
                        const int bidx = R / 1025, nn = R - bidx * 1025;
                        dst[((size_t)(bidx * 12 + h) * 1025 + nn) * 64 + d0] =
                            __float2half_rn((acc[im][in][reg] + bcol[in]) * scl);
                    }
                }
            }
        }
    } else {
#pragma unroll
        for (int im = 0; im < 4; ++im) {
            const int Rb2 = rb + wm * 64 + im * 16 + q * 4;
#pragma unroll
            for (int reg = 0; reg < 4; ++reg) {
                const int R = Rb2 + reg;
                if (R < kNT) {
#pragma unroll
                    for (int in = 0; in < 4; ++in) {
                        const int Ncol = cb + wn * 64 + in * 16 + ln;
                        OutF[(size_t)R * 768 + Ncol] = acc[im][in][reg] + bcol[in];
                    }
                }
            }
        }
    }
}

// ---------------- K2: landmark pooling (fp16 src -> fp32 landmarks) ---------
__global__ __launch_bounds__(64) void pool_kernel(
    const __half* __restrict__ Qh, const __half* __restrict__ Kh,
    float* __restrict__ QM, float* __restrict__ KM)
{
    const int d  = threadIdx.x;
    const int m  = blockIdx.x;
    const int bh = blockIdx.y;
    const __half* sb = (blockIdx.z ? Kh : Qh) + (size_t)bh * kN * 64;
    float* dst = blockIdx.z ? KM : QM;
    float v;
    if (m == 0) {
        v = __half2float(sb[d]);
    } else {
        int l = m - 1, a = l >> 3, e = l & 7;
        const __half* base = sb + (size_t)(1 + a * 128 + e * 4) * 64 + d;
        float s = 0.f;
#pragma unroll
        for (int b4 = 0; b4 < 4; ++b4)
#pragma unroll
            for (int f = 0; f < 4; ++f)
                s += __half2float(base[(b4 * 32 + f) * 64]);
        v = s * 0.0625f;
    }
    dst[(size_t)bh * 65 * 64 + m * 64 + d] = v;
}

// ---------------- K3: maxC[bh][m] = max_n qm[m].k[n] -----------------------
__global__ __launch_bounds__(256) void maxc_kernel(
    const float* __restrict__ QM, const __half* __restrict__ Kg,
    float* __restrict__ MAXC)
{
    __shared__ float QmT[64][68];   // [k][m]
    __shared__ float KtT[64][68];   // [k][nn]
    __shared__ float red[65][17];
    const int t = threadIdx.x, bh = blockIdx.x;
    const float* qm = QM + (size_t)bh * 4160;
    const __half* Kb = Kg + (size_t)bh * 65600;

    for (int s = 0; s < 5; ++s) {
        int idx = t + s * 256;
        if (idx < 1040) {
            int r = idx >> 4, c = idx & 15;
            float4 v = *(const float4*)(qm + r * 64 + c * 4);
            QmT[c * 4 + 0][r] = v.x; QmT[c * 4 + 1][r] = v.y;
            QmT[c * 4 + 2][r] = v.z; QmT[c * 4 + 3][r] = v.w;
        }
    }
    const int tm = t >> 4, tn = t & 15;
    float mx[5];
#pragma unroll
    for (int i = 0; i < 5; ++i) mx[i] = -3.4e38f;

    for (int nt = 0; nt < 17; ++nt) {
        const int n0 = nt * 64;
        __syncthreads();
        for (int s = 0; s < 4; ++s) {
            int idx = t + s * 256;
            int r = idx >> 4, c = idx & 15;
            int n = n0 + r;
            float4 v = make_float4(0.f, 0.f, 0.f, 0.f);
            if (n < kN) v = loadh4(Kb + (size_t)n * 64 + c * 4);
            KtT[c * 4 + 0][r] = v.x; KtT[c * 4 + 1][r] = v.y;
            KtT[c * 4 + 2][r] = v.z; KtT[c * 4 + 3][r] = v.w;
        }
        __syncthreads();
        float acc[5][4];
#pragma unroll
        for (int i = 0; i < 5; ++i)
#pragma unroll
            for (int j = 0; j < 4; ++j) acc[i][j] = 0.f;
        for (int k = 0; k < 64; ++k) {
            float a[5], b[4];
            float4 av = *(const float4*)&QmT[k][tm * 4];
            a[0] = av.x; a[1] = av.y; a[2] = av.z; a[3] = av.w;
            a[4] = (tm == 0) ? QmT[k][64] : 0.f;
            float4 bv = *(const float4*)&KtT[k][tn * 4];
            b[0] = bv.x; b[1] = bv.y; b[2] = bv.z; b[3] = bv.w;
#pragma unroll
            for (int i = 0; i < 5; ++i)
#pragma unroll
                for (int j = 0; j < 4; ++j)
                    acc[i][j] = fmaf(a[i], b[j], acc[i][j]);
        }
#pragma unroll
        for (int j = 0; j < 4; ++j) {
            if (n0 + tn * 4 + j < kN) {
#pragma unroll
                for (int i = 0; i < 5; ++i) mx[i] = fmaxf(mx[i], acc[i][j]);
            }
        }
    }
    __syncthreads();
#pragma unroll
    for (int i = 0; i < 4; ++i) red[tm * 4 + i][tn] = mx[i];
    if (tm == 0) red[64][tn] = mx[4];
    __syncthreads();
    if (t < 65) {
        float v = red[t][0];
        for (int c = 1; c < 16; ++c) v = fmaxf(v, red[t][c]);
        MAXC[(size_t)bh * 65 + t] = v;
    }
}

// ---------------- K4: expB = exp(max(qm@km^T - maxC, -88)); row/col sums ----
__global__ __launch_bounds__(256) void expb_kernel(
    const float* __restrict__ QM, const float* __restrict__ KM,
    const float* __restrict__ MAXC, float* __restrict__ EXPB,
    float* __restrict__ RC)
{
    __shared__ float Qs[65][68];
    __shared__ float Ks[65][68];
    __shared__ float SB[65][68];
    __shared__ float mc[65];
    __shared__ float rs[65], cs[65];
    const int t = threadIdx.x, bh = blockIdx.x;
    const float* qm = QM + (size_t)bh * 4160;
    const float* km = KM + (size_t)bh * 4160;
    for (int s = 0; s < 5; ++s) {
        int idx = t + s * 256;
        if (idx < 1040) {
            int r = idx >> 4, c = (idx & 15) * 4;
            *(float4*)&Qs[r][c] = *(const float4*)(qm + r * 64 + c);
            *(float4*)&Ks[r][c] = *(const float4*)(km + r * 64 + c);
        }
    }
    if (t < 65) mc[t] = MAXC[(size_t)bh * 65 + t];
    __syncthreads();
    for (int s = 0; s < 17; ++s) {
        int o = t + s * 256;
        if (o < 4225) {
            int i = o / 65, j = o % 65;
            float av = 0.f;
            for (int k = 0; k < 64; k += 4) {
                float4 a = *(const float4*)&Qs[i][k];
                float4 b = *(const float4*)&Ks[j][k];
                av = fmaf(a.x, b.x, av); av = fmaf(a.y, b.y, av);
                av = fmaf(a.z, b.z, av); av = fmaf(a.w, b.w, av);
            }
            float e = __expf(fmaxf(av - mc[i], -88.f));
            SB[i][j] = e;
            EXPB[(size_t)bh * 4225 + o] = e;
        }
    }
    __syncthreads();
    if (t < 65) {
        float r = 0.f, c = 0.f;
        for (int j = 0; j < 65; ++j) r += SB[t][j];
        for (int i = 0; i < 65; ++i) c += SB[i][t];
        rs[t] = r; cs[t] = c;
    }
    __syncthreads();
    if (t == 0) {
        float rm = 0.f, cm2 = 0.f;
        for (int i = 0; i < 65; ++i) { rm = fmaxf(rm, rs[i]); cm2 = fmaxf(cm2, cs[i]); }
        RC[bh * 2] = rm; RC[bh * 2 + 1] = cm2;
    }
}

// ---------------- K5: alpha = 1/(global_max_rowsum * global_max_colsum + eps)
__global__ __launch_bounds__(256) void alpha_kernel(
    const float* __restrict__ RC, float* __restrict__ GMX)
{
    __shared__ float sr[256], sc[256];
    const int t = threadIdx.x;
    float rm = 0.f, cm = 0.f;
    for (int i = t; i < kBH; i += 256) {
        rm = fmaxf(rm, RC[2 * i]);
        cm = fmaxf(cm, RC[2 * i + 1]);
    }
    sr[t] = rm; sc[t] = cm;
    __syncthreads();
    for (int s = 128; s > 0; s >>= 1) {
        if (t < s) { sr[t] = fmaxf(sr[t], sr[t + s]); sc[t] = fmaxf(sc[t], sc[t + s]); }
        __syncthreads();
    }
    if (t == 0) GMX[0] = 1.f / (sr[0] * sc[0] + 1e-15f);
}

// ---------------- K7: T1 = expC @ v_aug  (recompute S_C; no expC storage) ---
__global__ __launch_bounds__(256) void t1_kernel(
    const float* __restrict__ QM, const __half* __restrict__ Kg,
    const __half* __restrict__ Vg, const float* __restrict__ MAXC,
    float* __restrict__ T1)
{
    __shared__ float QmT[64][68];   // [k][m]
    __shared__ float Wt[64][68];    // K-tile transposed / V-tile
    __shared__ float ET[64][68];    // [nn][m] expC tile
    __shared__ float mc[65];
    const int t = threadIdx.x, bh = blockIdx.x;
    const float* qm = QM + (size_t)bh * 4160;
    const __half* Kb = Kg + (size_t)bh * 65600;
    const __half* Vb = Vg + (size_t)bh * 65600;

    for (int s = 0; s < 5; ++s) {
        int idx = t + s * 256;
        if (idx < 1040) {
            int r = idx >> 4, c = idx & 15;
            float4 v = *(const float4*)(qm + r * 64 + c * 4);
            QmT[c * 4 + 0][r] = v.x; QmT[c * 4 + 1][r] = v.y;
            QmT[c * 4 + 2][r] = v.z; QmT[c * 4 + 3][r] = v.w;
        }
    }
    if (t < 65) mc[t] = MAXC[(size_t)bh * 65 + t];
    const int tm = t >> 4, tn = t & 15;
    float acc2[5][5];
#pragma unroll
    for (int i = 0; i < 5; ++i)
#pragma unroll
        for (int j = 0; j < 5; ++j) acc2[i][j] = 0.f;

    for (int nt = 0; nt < 17; ++nt) {
        const int n0 = nt * 64;
        __syncthreads();
        for (int s = 0; s < 4; ++s) {
            int idx = t + s * 256;
            int r = idx >> 4, c = idx & 15;
            int n = n0 + r;
            float4 v = make_float4(0.f, 0.f, 0.f, 0.f);
            if (n < kN) v = loadh4(Kb + (size_t)n * 64 + c * 4);
            Wt[c * 4 + 0][r] = v.x; Wt[c * 4 + 1][r] = v.y;
            Wt[c * 4 + 2][r] = v.z; Wt[c * 4 + 3][r] = v.w;
        }
        __syncthreads();
        {
            float acc[5][4];
#pragma unroll
            for (int i = 0; i < 5; ++i)
#pragma unroll
                for (int j = 0; j < 4; ++j) acc[i][j] = 0.f;
            for (int k = 0; k < 64; ++k) {
                float a[5], b[4];
                float4 av = *(const float4*)&QmT[k][tm * 4];
                a[0] = av.x; a[1] = av.y; a[2] = av.z; a[3] = av.w;
                a[4] = (tm == 0) ? QmT[k][64] : 0.f;
                float4 bv = *(const float4*)&Wt[k][tn * 4];
                b[0] = bv.x; b[1] = bv.y; b[2] = bv.z; b[3] = bv.w;
#pragma unroll
                for (int i = 0; i < 5; ++i)
#pragma unroll
                    for (int j = 0; j < 4; ++j)
                        acc[i][j] = fmaf(a[i], b[j], acc[i][j]);
            }
#pragma unroll
            for (int j = 0; j < 4; ++j) {
                int nn = tn * 4 + j;
                bool valid = (n0 + nn) < kN;
#pragma unroll
                for (int i = 0; i < 4; ++i)
                    ET[nn][tm * 4 + i] = valid ? __expf(acc[i][j] - mc[tm * 4 + i]) : 0.f;
                if (tm == 0)
                    ET[nn][64] = valid ? __expf(acc[4][j] - mc[64]) : 0.f;
            }
        }
        __syncthreads();
        for (int s = 0; s < 4; ++s) {
            int idx = t + s * 256;
            int r = idx >> 4, c = idx & 15;
            int n = n0 + r;
            float4 v = make_float4(0.f, 0.f, 0.f, 0.f);
            if (n < kN) v = loadh4(Vb + (size_t)n * 64 + c * 4);
            *(float4*)&Wt[r][c * 4] = v;
        }
        if (t < 64) Wt[t][64] = 1.f;
        __syncthreads();
        for (int nn = 0; nn < 64; ++nn) {
            float a[5], b[5];
            float4 av = *(const float4*)&ET[nn][tm * 4];
            a[0] = av.x; a[1] = av.y; a[2] = av.z; a[3] = av.w;
            a[4] = (tm == 0) ? ET[nn][64] : 0.f;
            float4 bv = *(const float4*)&Wt[nn][tn * 4];
            b[0] = bv.x; b[1] = bv.y; b[2] = bv.z; b[3] = bv.w;
            b[4] = (tn == 0) ? Wt[nn][64] : 0.f;
#pragma unroll
            for (int i = 0; i < 5; ++i)
#pragma unroll
                for (int j = 0; j < 5; ++j)
                    acc2[i][j] = fmaf(a[i], b[j], acc2[i][j]);
        }
    }
    float* T1b = T1 + (size_t)bh * 4225;
#pragma unroll
    for (int i = 0; i < 5; ++i) {
        if (i == 4 && tm != 0) continue;
        int m = (i < 4) ? tm * 4 + i : 64;
#pragma unroll
        for (int j = 0; j < 5; ++j) {
            if (j == 4 && tn != 0) continue;
            int jc = (j < 4) ? tn * 4 + j : 64;
            T1b[m * 65 + jc] = acc2[i][j];
        }
    }
}

// ---------------- K6: Newton-Schulz pinv (6 iters) + T2 = Z @ T1 ------------
__device__ __forceinline__ void mm65(const float (*Op1)[68], const float (*Op2)[68],
                                     float (*Dst)[68], const float (*Pre)[68],
                                     float c0, float c1, int tm, int tj)
{
    float acc[5][5];
#pragma unroll
    for (int i = 0; i < 5; ++i)
#pragma unroll
        for (int j = 0; j < 5; ++j) acc[i][j] = 0.f;
    for (int k = 0; k < 65; ++k) {
        float a[5], b[5];
        a[0] = Op1[tm * 4 + 0][k]; a[1] = Op1[tm * 4 + 1][k];
        a[2] = Op1[tm * 4 + 2][k]; a[3] = Op1[tm * 4 + 3][k];
        a[4] = (tm == 0) ? Op1[64][k] : 0.f;
        float4 bv = *(const float4*)&Op2[k][tj * 4];
        b[0] = bv.x; b[1] = bv.y; b[2] = bv.z; b[3] = bv.w;
        b[4] = (tj == 0) ? Op2[k][64] : 0.f;
#pragma unroll
        for (int i = 0; i < 5; ++i)
#pragma unroll
            for (int j = 0; j < 5; ++j)
                acc[i][j] = fmaf(a[i], b[j], acc[i][j]);
    }
    float val[5][5];
#pragma unroll
    for (int i = 0; i < 5; ++i) {
        int mi = (i < 4) ? tm * 4 + i : 64;
#pragma unroll
        for (int j = 0; j < 5; ++j) {
            int jc = (j < 4) ? tj * 4 + j : 64;
            val[i][j] = c1 * (c0 * Pre[mi][jc] - acc[i][j]);
        }
    }
    __syncthreads();
#pragma unroll
    for (int i = 0; i < 5; ++i) {
        if (i == 4 && tm != 0) continue;
        int mi = (i < 4) ? tm * 4 + i : 64;
#pragma unroll
        for (int j = 0; j < 5; ++j) {
            if (j == 4 && tj != 0) continue;
            int jc = (j < 4) ? tj * 4 + j : 64;
            Dst[mi][jc] = val[i][j];
        }
    }
    __syncthreads();
}

__global__ __launch_bounds__(256) void pinv_kernel(
    const float* __restrict__ EXPB, const float* __restrict__ T1,
    const float* __restrict__ GMX, float* __restrict__ T2)
{
    __shared__ float Wb[65][68];
    __shared__ float Zb[65][68];
    __shared__ float Ab[65][68];
    const int t = threadIdx.x, bh = blockIdx.x;
    const int tm = t >> 4, tj = t & 15;
    const float alpha = GMX[0];
    const float* X = EXPB + (size_t)bh * 4225;
    for (int s = 0; s < 17; ++s) {
        int o = t + s * 256;
        if (o < 4225) Wb[o / 65][o % 65] = X[o];
    }
    __syncthreads();
    for (int s = 0; s < 17; ++s) {   // Z = alpha * X^T
        int o = t + s * 256;
        if (o < 4225) { int i = o / 65, j = o % 65; Zb[i][j] = alpha * Wb[j][i]; }
    }
    __syncthreads();
    for (int it = 0; it < 6; ++it) {
        if (it > 0) {
            for (int s = 0; s < 17; ++s) {
                int o = t + s * 256;
                if (o < 4225) Wb[o / 65][o % 65] = X[o];
            }
            __syncthreads();
        }
        mm65(Wb, Zb, Ab, Wb, 0.f,  -1.f,  tm, tj);  // A = X@Z
        mm65(Ab, Ab, Wb, Ab, 7.f,   1.f,  tm, tj);  // U = 7A - A@A    -> W
        mm65(Ab, Wb, Ab, Ab, 15.f,  1.f,  tm, tj);  // V = 15A - A@U   -> A
        mm65(Zb, Ab, Zb, Zb, 13.f,  0.25f, tm, tj); // Z = .25(13Z - Z@V)
    }
    for (int s = 0; s < 17; ++s) {
        int o = t + s * 256;
        if (o < 4225) Wb[o / 65][o % 65] = T1[(size_t)bh * 4225 + o];
    }
    __syncthreads();
    {
        float acc[5][5];
#pragma unroll
        for (int i = 0; i < 5; ++i)
#pragma unroll
            for (int j = 0; j < 5; ++j) acc[i][j] = 0.f;
        for (int k = 0; k < 65; ++k) {
            float a[5], b[5];
            a[0] = Zb[tm * 4 + 0][k]; a[1] = Zb[tm * 4 + 1][k];
            a[2] = Zb[tm * 4 + 2][k]; a[3] = Zb[tm * 4 + 3][k];
            a[4] = (tm == 0) ? Zb[64][k] : 0.f;
            float4 bv = *(const float4*)&Wb[k][tj * 4];
            b[0] = bv.x; b[1] = bv.y; b[2] = bv.z; b[3] = bv.w;
            b[4] = (tj == 0) ? Wb[k][64] : 0.f;
#pragma unroll
            for (int i = 0; i < 5; ++i)
#pragma unroll
                for (int j = 0; j < 5; ++j)
                    acc[i][j] = fmaf(a[i], b[j], acc[i][j]);
        }
        float* dst = T2 + (size_t)bh * 4225;
#pragma unroll
        for (int i = 0; i < 5; ++i) {
            if (i == 4 && tm != 0) continue;
            int mi = (i < 4) ? tm * 4 + i : 64;
#pragma unroll
            for (int j = 0; j < 5; ++j) {
                if (j == 4 && tj != 0) continue;
                int jc = (j < 4) ? tj * 4 + j : 64;
                dst[mi * 65 + jc] = acc[i][j];
            }
        }
    }
}

// ---------------- K8: prod = expA @ T2 ; ctx -> fp16 (B,N,C) ----------------
__global__ __launch_bounds__(256) void prod_kernel(
    const __half* __restrict__ Qg, const float* __restrict__ KM,
    const float* __restrict__ T2, __half* __restrict__ CTXh)
{
    __shared__ float Sh1[65][68];   // KmT [k][m] (phase1) then T2 (phase2)
    __shared__ float QtT[64][68];   // [k][nn]
    __shared__ float EA[64][69];    // raw S -> expA -> ctx-tile
    __shared__ float den[64];
    __shared__ float pm[64][4];
    const int t  = threadIdx.x;
    const int nt = blockIdx.x, bh = blockIdx.y;
    const int bq = bh / 12, h = bh % 12;
    const int n0 = nt * 64;
    const float* km = KM + (size_t)bh * 4160;
    const __half* Qb = Qg + (size_t)bh * 65600;

    for (int s = 0; s < 5; ++s) {
        int idx = t + s * 256;
        if (idx < 1040) {
            int r = idx >> 4, c = idx & 15;
            float4 v = *(const float4*)(km + r * 64 + c * 4);
            Sh1[c * 4 + 0][r] = v.x; Sh1[c * 4 + 1][r] = v.y;
            Sh1[c * 4 + 2][r] = v.z; Sh1[c * 4 + 3][r] = v.w;
        }
    }
    for (int s = 0; s < 4; ++s) {
        int idx = t + s * 256;
        int r = idx >> 4, c = idx & 15;
        int n = n0 + r;
        float4 v = make_float4(0.f, 0.f, 0.f, 0.f);
        if (n < kN) v = loadh4(Qb + (size_t)n * 64 + c * 4);
        QtT[c * 4 + 0][r] = v.x; QtT[c * 4 + 1][r] = v.y;
        QtT[c * 4 + 2][r] = v.z; QtT[c * 4 + 3][r] = v.w;
    }
    __syncthreads();
    {   // phase1: raw S_A tile
        const int tm = t >> 4, tn = t & 15;
        float acc[5][4];
#pragma unroll
        for (int i = 0; i < 5; ++i)
#pragma unroll
            for (int j = 0; j < 4; ++j) acc[i][j] = 0.f;
        for (int k = 0; k < 64; ++k) {
            float a[5], b[4];
            float4 av = *(const float4*)&Sh1[k][tm * 4];
            a[0] = av.x; a[1] = av.y; a[2] = av.z; a[3] = av.w;
            a[4] = (tm == 0) ? Sh1[k][64] : 0.f;
            float4 bv = *(const float4*)&QtT[k][tn * 4];
            b[0] = bv.x; b[1] = bv.y; b[2] = bv.z; b[3] = bv.w;
#pragma unroll
            for (int i = 0; i < 5; ++i)
#pragma unroll
                for (int j = 0; j < 4; ++j)
                    acc[i][j] = fmaf(a[i], b[j], acc[i][j]);
        }
#pragma unroll
        for (int j = 0; j < 4; ++j) {
            int nn = tn * 4 + j;
#pragma unroll
            for (int i = 0; i < 4; ++i) EA[nn][tm * 4 + i] = acc[i][j];
            if (tm == 0) EA[nn][64] = acc[4][j];
        }
    }
    __syncthreads();
    {   // row max + exp
        const int rr = t & 63, mg = t >> 6;
        float mx = -3.4e38f;
        for (int s = 0; s < 17; ++s) { int m = mg + 4 * s; if (m < 65) mx = fmaxf(mx, EA[rr][m]); }
        pm[rr][mg] = mx;
        __syncthreads();
        float mt2 = fmaxf(fmaxf(pm[rr][0], pm[rr][1]), fmaxf(pm[rr][2], pm[rr][3]));
        for (int s = 0; s < 17; ++s) { int m = mg + 4 * s; if (m < 65) EA[rr][m] = __expf(EA[rr][m] - mt2); }
    }
    for (int s = 0; s < 17; ++s) {
        int o = t + s * 256;
        if (o < 4225) Sh1[o / 65][o % 65] = T2[(size_t)bh * 4225 + o];
    }
    __syncthreads();
    {   // phase2: prod = EA @ T2, divide, stash ctx tile
        const int tr = t & 15, tjg = t >> 4;
        float acc2[4][5];
#pragma unroll
        for (int i = 0; i < 4; ++i)
#pragma unroll
            for (int j = 0; j < 5; ++j) acc2[i][j] = 0.f;
        for (int m = 0; m < 65; ++m) {
            float a[4], b[5];
            a[0] = EA[tr * 4 + 0][m]; a[1] = EA[tr * 4 + 1][m];
            a[2] = EA[tr * 4 + 2][m]; a[3] = EA[tr * 4 + 3][m];
            float4 bv = *(const float4*)&Sh1[m][tjg * 4];
            b[0] = bv.x; b[1] = bv.y; b[2] = bv.z; b[3] = bv.w;
            b[4] = (tjg == 0) ? Sh1[m][64] : 0.f;
#pragma unroll
            for (int i = 0; i < 4; ++i)
#pragma unroll
                for (int j = 0; j < 5; ++j)
                    acc2[i][j] = fmaf(a[i], b[j], acc2[i][j]);
        }
        if (tjg == 0) {
#pragma unroll
            for (int ii = 0; ii < 4; ++ii) den[tr * 4 + ii] = acc2[ii][4];
        }
        __syncthreads();
#pragma unroll
        for (int ii = 0; ii < 4; ++ii) {
            int nn = tr * 4 + ii;
            float dv = fmaxf(den[nn], 1e-8f);
#pragma unroll
            for (int jj = 0; jj < 4; ++jj)
                EA[nn][tjg * 4 + jj] = acc2[ii][jj] / dv;
        }
    }
    __syncthreads();
    {   // write ctx fp16: [b, n, h*64 + c]
        const int c = t & 63, rg = t >> 6;
        for (int s = 0; s < 16; ++s) {
            int r = rg + 4 * s;
            int n = n0 + r;
            if (n < kN)
                CTXh[((size_t)bq * 1025 + n) * 768 + h * 64 + c] = __float2half_rn(EA[r][c]);
        }
    }
}

// ---------------------------------------------------------------------------
extern "C" void kernel_launch(void* const* d_in, const int* in_sizes, int n_in,
                              void* d_out, int out_size, void* d_ws, size_t ws_size,
                              hipStream_t stream)
{
    const float* x      = (const float*)d_in[0];
    const float* qkv_w  = (const float*)d_in[1];
    const float* qkv_b  = (const float*)d_in[2];
    const float* proj_w = (const float*)d_in[3];
    const float* proj_b = (const float*)d_in[4];
    float* out = (float*)d_out;

    // d_out: [Xh (QSZ halves) | Qh (QSZ halves)]; both dead before gemm_proj.
    __half* Xh = (__half*)d_out;
    __half* Qh = Xh + QSZ;

    // ws layout
    __half* Kh   = (__half*)d_ws;               // QSZ halves
    __half* Vh   = Kh + QSZ;                    // QSZ halves
    __half* CTXh = Kh;                          // aliases Kh (dead after t1)
    float*  QM   = (float*)(Vh + QSZ);          // 2*QSZ halves == QSZ floats
    float*  KM   = QM + QMSZ;
    float*  MAXC = KM + QMSZ;
    float*  EXPB = MAXC + (size_t)kBH * 65;
    float*  T1   = EXPB + SBSZ;
    float*  T2   = T1 + SBSZ;
    float*  RC   = T2 + SBSZ;
    float*  GMX  = RC + (size_t)kBH * 2;
    // fp16 transposed weights, 16B-aligned after GMX
    size_t woff = (size_t)(GMX + 1 - (float*)d_ws);
    woff = (woff + 3) & ~(size_t)3;             // align to 16 B in floats
    __half* WqkvT = (__half*)((float*)d_ws + woff);   // 2304*768 halves
    __half* WprojT = WqkvT + (size_t)2304 * 768;      // 768*768 halves

    cvt_f32_f16  <<<dim3((int)(QSZ / 4 / 256)), 256, 0, stream>>>(x, Xh, (int)(QSZ / 4));
    cvt_transpose<<<dim3(72, 24), dim3(32, 8), 0, stream>>>(qkv_w, WqkvT, 768, 2304);
    cvt_transpose<<<dim3(24, 24), dim3(32, 8), 0, stream>>>(proj_w, WprojT, 768, 768);

    gemm_mfma<0><<<dim3(18, 257), 256, 0, stream>>>(Xh, WqkvT, qkv_b,
                                                    nullptr, Qh, Kh, Vh);
    pool_kernel<<<dim3(65, kBH, 2), 64, 0, stream>>>(Qh, Kh, QM, KM);
    maxc_kernel<<<dim3(kBH), 256, 0, stream>>>(QM, Kh, MAXC);
    expb_kernel<<<dim3(kBH), 256, 0, stream>>>(QM, KM, MAXC, EXPB, RC);
    alpha_kernel<<<dim3(1), 256, 0, stream>>>(RC, GMX);
    t1_kernel  <<<dim3(kBH), 256, 0, stream>>>(QM, Kh, Vh, MAXC, T1);
    pinv_kernel<<<dim3(kBH), 256, 0, stream>>>(EXPB, T1, GMX, T2);
    prod_kernel<<<dim3(17, kBH), 256, 0, stream>>>(Qh, KM, T2, CTXh);
    gemm_mfma<1><<<dim3(6, 257), 256, 0, stream>>>(CTXh, WprojT, proj_b,
                                                   out, nullptr, nullptr, nullptr);
}